// Round 4
// baseline (11958.266 us; speedup 1.0000x reference)
//
#include <hip/hip_runtime.h>
#include <math.h>

#define LIN 256
#define LOUT 64
#define NENDO 48

typedef __attribute__((ext_vector_type(8))) short short8;
typedef __attribute__((ext_vector_type(4))) float f32x4;
typedef __attribute__((ext_vector_type(16))) float f32x16;

// ---------------- ws layout (bytes) ----------------
constexpr size_t O_APE0 = 0;                      // 128 T x 68 c x 2 spl x 512 sh x 2B
constexpr size_t O_APE1 = 17825792;               // 128 x 128 x 2 x 512 x 2
constexpr size_t O_APD0 = 51380224;
constexpr size_t O_APD1 = 69206016;
constexpr size_t O_SRCF = 102760448;              // 256 steps x 16384 B (frag order)
constexpr size_t O_EXH  = 106954752;              // [64t][64b][16e] ushort
constexpr size_t O_EXL  = 107085824;
constexpr size_t O_H0F  = 107216896;              // 2 x 262144 (frag order)
constexpr size_t O_H1F  = 107741184;              // 2 x 262144
constexpr size_t O_XF   = 108265472;              // 2 x 16384
constexpr size_t O_H1KM = 108298240;              // fp32 [1024][64]
constexpr size_t O_BIAS = 108560384;              // 4 x [1024][4] fp32
constexpr size_t O_BAR  = 108625920;              // 2048 ints
// total 108,634,112 B

__device__ __forceinline__ unsigned short f2bh(float x) {
    unsigned int u = __float_as_uint(x);
    unsigned int r = (u + 0x7fffu + ((u >> 16) & 1u)) >> 16;
    return (unsigned short)r;
}
__device__ __forceinline__ float bh2f(unsigned short h) {
    return __uint_as_float(((unsigned int)h) << 16);
}
__device__ __forceinline__ float sigf(float x) { return 1.0f / (1.0f + expf(-x)); }

// frag-order state layout: [ks(16k)][bt(2)][spl(2)][64 lanes][8 e] shorts
// element (k, b): ks=k>>4, lane=(b&31)+32*((k>>3)&1), e=k&7, bt=b>>5
__device__ __forceinline__ size_t frag_off(int k, int b, int spl) {
    return (size_t)(k >> 4) * 2048 + (size_t)(b >> 5) * 1024 + (size_t)spl * 512
         + (size_t)((b & 31) + 32 * ((k >> 3) & 1)) * 8 + (k & 7);
}

// ---------------- A pre-pack: 32-row tiles, 16-k chunks, 32x32x16 A-frag order ----------------
// out[T][c][spl][lane*8+e]: row p = T*32 + (lane&31), k = c*16 + (lane>>5)*8 + e
__global__ void pack_a32(const float* __restrict__ Wx, const float* __restrict__ Wh,
                         unsigned short* __restrict__ out, int KX, int NC)
{
    const int n = 128 * NC * 512;
    for (int j = blockIdx.x * blockDim.x + threadIdx.x; j < n; j += gridDim.x * blockDim.x) {
        int r2 = j & 511;
        int c = (j >> 9) % NC;
        int T = (j >> 9) / NC;
        int l = r2 >> 3, e = r2 & 7;
        int p = T * 32 + (l & 31);
        int hcol = p >> 2, gate = p & 3;
        int k = c * 16 + (l >> 5) * 8 + e;
        float v = (k < KX) ? Wx[(gate * 1024 + hcol) * KX + k]
                           : Wh[(gate * 1024 + hcol) * 1024 + (k - KX)];
        unsigned short h = f2bh(v);
        size_t o = ((size_t)(T * NC + c) * 2) * 512 + r2;
        out[o] = h;
        out[o + 512] = f2bh(v - bh2f(h));
    }
}

__global__ void pack_bias_kernel(const float* a0, const float* b0, const float* a1, const float* b1,
                                 const float* a2, const float* b2, const float* a3, const float* b3,
                                 float* d)
{
    int i = blockIdx.x * blockDim.x + threadIdx.x;
    if (i >= 4096) return;
    int hcol = i >> 2, gate = i & 3, s = (gate << 10) + hcol;
    d[i] = a0[s] + b0[s];
    d[4096 + i] = a1[s] + b1[s];
    d[8192 + i] = a2[s] + b2[s];
    d[12288 + i] = a3[s] + b3[s];
}

// ---------------- misc prep ----------------
__global__ void prep_misc(const float* __restrict__ src, const float* __restrict__ trg,
                          char* __restrict__ wsb)
{
    unsigned short* hz = (unsigned short*)(wsb + O_H0F);   // h0f+h1f contiguous: 524288 shorts
    int* bar = (int*)(wsb + O_BAR);
    unsigned short* srcf = (unsigned short*)(wsb + O_SRCF);
    unsigned short* exh = (unsigned short*)(wsb + O_EXH);
    unsigned short* exl = (unsigned short*)(wsb + O_EXL);
    unsigned short* xf0 = (unsigned short*)(wsb + O_XF);
    const int N0 = 524288, N1 = 2048, N2 = 1048576, N3 = 65536, N4 = 4096;
    const int TOT = N0 + N1 + N2 + N3 + N4;
    for (int i = blockIdx.x * blockDim.x + threadIdx.x; i < TOT; i += gridDim.x * blockDim.x) {
        if (i < N0) {
            hz[i] = 0;
        } else if (i < N0 + N1) {
            bar[i - N0] = 0;
        } else if (i < N0 + N1 + N2) {
            int j = i - (N0 + N1);
            int t = j >> 12, b = (j >> 6) & 63, k = j & 63;
            float v = src[(b * LIN + t) * 64 + k];
            unsigned short h = f2bh(v);
            unsigned short* d = srcf + (size_t)t * 8192;
            d[frag_off(k, b, 0)] = h;
            d[frag_off(k, b, 1)] = f2bh(v - bh2f(h));
        } else if (i < N0 + N1 + N2 + N3) {
            int j = i - (N0 + N1 + N2);
            int t = j >> 10, b = (j >> 4) & 63, e = j & 15;
            float v = trg[(b * LOUT + t) * 64 + NENDO + e];
            unsigned short h = f2bh(v);
            exh[j] = h; exl[j] = f2bh(v - bh2f(h));
        } else {
            int j = i - (N0 + N1 + N2 + N3);
            int b = j >> 6, k = j & 63;
            float v = src[(b * LIN + (LIN - 1)) * 64 + k];
            unsigned short h = f2bh(v);
            xf0[frag_off(k, b, 0)] = h;
            xf0[frag_off(k, b, 1)] = f2bh(v - bh2f(h));
        }
    }
}

// ---------------- persistent kernel helpers ----------------
template <int CNT>
__device__ __forceinline__ void load_a(const unsigned short* __restrict__ ap, int T, int NC,
                                       int base, int l, short8* A)
{
#pragma unroll
    for (int i = 0; i < CNT; i++) {
#pragma unroll
        for (int s = 0; s < 2; s++)
            A[i * 2 + s] = *(const short8*)(ap + (((size_t)T * NC + (base + i)) * 2 + s) * 512 + l * 8);
    }
}

template <int CNT>
__device__ __forceinline__ void compute_ph(const unsigned short* __restrict__ B1, int S,
                                           const unsigned short* __restrict__ B2,
                                           int base, const short8* A, int l,
                                           f32x16& a0, f32x16& a1)
{
#pragma unroll
    for (int i = 0; i < CNT; i++) {
        int ks = base + i;
        const unsigned short* fb = (ks < S) ? (B1 + (size_t)ks * 2048) : (B2 + (size_t)(ks - S) * 2048);
        short8 bh0 = *(const short8*)(fb + l * 8);
        short8 bl0 = *(const short8*)(fb + 512 + l * 8);
        short8 bh1 = *(const short8*)(fb + 1024 + l * 8);
        short8 bl1 = *(const short8*)(fb + 1536 + l * 8);
        short8 ah = A[i * 2], al = A[i * 2 + 1];
        a0 = __builtin_amdgcn_mfma_f32_32x32x16_bf16(ah, bh0, a0, 0, 0, 0);
        a1 = __builtin_amdgcn_mfma_f32_32x32x16_bf16(ah, bh1, a1, 0, 0, 0);
        a0 = __builtin_amdgcn_mfma_f32_32x32x16_bf16(ah, bl0, a0, 0, 0, 0);
        a1 = __builtin_amdgcn_mfma_f32_32x32x16_bf16(ah, bl1, a1, 0, 0, 0);
        a0 = __builtin_amdgcn_mfma_f32_32x32x16_bf16(al, bh0, a0, 0, 0, 0);
        a1 = __builtin_amdgcn_mfma_f32_32x32x16_bf16(al, bh1, a1, 0, 0, 0);
    }
}

// reduce across 8 kt-waves, apply LSTM pointwise, write h frag-order (+ optional k-major f32)
__device__ __forceinline__ void reduce_epi(float* ldsf, f32x16& a0, f32x16& a1,
                                           int w, int l, int T,
                                           const float* __restrict__ biasP,
                                           unsigned short* __restrict__ Hout,
                                           float* __restrict__ km, float* creg)
{
    const int l31 = l & 31, l5 = l >> 5;
    __syncthreads();
#pragma unroll
    for (int j = 0; j < 16; j++) {
        ldsf[((w * 2 + 0) * 16 + j) * 64 + l] = a0[j];
        ldsf[((w * 2 + 1) * 16 + j) * 64 + l] = a1[j];
    }
    __syncthreads();
    if (w < 2) {
#pragma unroll
        for (int q = 0; q < 4; q++) {
            float gv[4];
#pragma unroll
            for (int j = 0; j < 4; j++) {
                float v = 0.0f;
#pragma unroll
                for (int kt = 0; kt < 8; kt++) v += ldsf[((kt * 2 + w) * 16 + (q * 4 + j)) * 64 + l];
                gv[j] = v;
            }
            int hcol = T * 8 + 2 * q + l5;
            int b = w * 32 + l31;
            const f32x4 bv = *(const f32x4*)(biasP + hcol * 4);
            float ig = sigf(gv[0] + bv[0]);
            float fg = sigf(gv[1] + bv[1]);
            float gg = tanhf(gv[2] + bv[2]);
            float og = sigf(gv[3] + bv[3]);
            float cv = fg * creg[q] + ig * gg;
            creg[q] = cv;
            float hv = og * tanhf(cv);
            if (km) km[hcol * 64 + b] = hv;
            unsigned short hh = f2bh(hv);
            unsigned short hl = f2bh(hv - bh2f(hh));
            size_t fo = (size_t)(T >> 1) * 2048 + (size_t)w * 1024
                      + (size_t)(l31 + 32 * (T & 1)) * 8 + (2 * q + l5);
            Hout[fo] = hh;
            Hout[fo + 512] = hl;
        }
    }
}

__device__ __forceinline__ void gridbar(int* bar, int& ep, int tid, int gblk)
{
    __syncthreads();
    ep++;
    if (tid == 0) {
        __threadfence();
        int grp = gblk >> 5;
        int a = atomicAdd(&bar[grp * 32], 1);
        if (a == ep * 32 - 1) atomicAdd(&bar[1024], 1);
        while (__hip_atomic_load(&bar[1024], __ATOMIC_RELAXED, __HIP_MEMORY_SCOPE_AGENT) < ep * 8)
            __builtin_amdgcn_s_sleep(4);
        __threadfence();
    }
    __syncthreads();
}

// ---------------- the persistent kernel ----------------
__global__ __launch_bounds__(512) void persist(char* __restrict__ wsb,
                                               const float* __restrict__ fcW,
                                               const float* __restrict__ fcb,
                                               float* __restrict__ out)
{
    __shared__ float ldsf[16384];  // 64 KB

    const unsigned short* apE0 = (const unsigned short*)(wsb + O_APE0);
    const unsigned short* apE1 = (const unsigned short*)(wsb + O_APE1);
    const unsigned short* apD0 = (const unsigned short*)(wsb + O_APD0);
    const unsigned short* apD1 = (const unsigned short*)(wsb + O_APD1);
    const unsigned short* srcf = (const unsigned short*)(wsb + O_SRCF);
    const unsigned short* exh = (const unsigned short*)(wsb + O_EXH);
    const unsigned short* exl = (const unsigned short*)(wsb + O_EXL);
    unsigned short* h0f[2] = { (unsigned short*)(wsb + O_H0F), (unsigned short*)(wsb + O_H0F + 262144) };
    unsigned short* h1f[2] = { (unsigned short*)(wsb + O_H1F), (unsigned short*)(wsb + O_H1F + 262144) };
    unsigned short* xf[2] = { (unsigned short*)(wsb + O_XF), (unsigned short*)(wsb + O_XF + 16384) };
    float* h1km = (float*)(wsb + O_H1KM);
    const float* biasB = (const float*)(wsb + O_BIAS);
    int* bar = (int*)(wsb + O_BAR);

    const int tid = threadIdx.x;
    const int l = tid & 63;
    const int w = tid >> 6;            // kt wave id 0..7
    const int g = blockIdx.x;
    const bool isL0 = g < 128;
    const int T = isL0 ? g : g - 128;
    const int base0 = (w < 4) ? w * 9 : 36 + (w - 4) * 8;   // L0-type K split (68 chunks)
    int ep = 0;

    short8 Areg[32];
    float creg[4] = {0.f, 0.f, 0.f, 0.f};

    // ---- load encoder A into registers ----
    if (isL0) {
        if (w < 4) load_a<9>(apE0, T, 68, base0, l, Areg);
        else       load_a<8>(apE0, T, 68, base0, l, Areg);
    } else {
        load_a<16>(apE1, T, 128, w * 16, l, Areg);
    }

    // ---- encoder: 257 slots; slot d runs L0(step d) and L1(step d-1) ----
    for (int d = 0; d <= LIN; d++) {
        if (isL0) {
            if (d < LIN) {
                f32x16 a0 = {}, a1 = {};
                const unsigned short* B1 = srcf + (size_t)d * 8192;
                const unsigned short* B2 = h0f[(d + 1) & 1];
                if (w < 4) compute_ph<9>(B1, 4, B2, base0, Areg, l, a0, a1);
                else       compute_ph<8>(B1, 4, B2, base0, Areg, l, a0, a1);
                reduce_epi(ldsf, a0, a1, w, l, T, biasB, h0f[d & 1], nullptr, creg);
            }
        } else {
            if (d >= 1) {
                f32x16 a0 = {}, a1 = {};
                const unsigned short* B1 = h0f[(d + 1) & 1];
                const unsigned short* B2 = h1f[(d + 1) & 1];
                compute_ph<16>(B1, 64, B2, w * 16, Areg, l, a0, a1);
                reduce_epi(ldsf, a0, a1, w, l, T, biasB + 4096, h1f[d & 1], nullptr, creg);
            }
        }
        gridbar(bar, ep, tid, g);
    }

    // ---- reload A for decoder ----
    if (isL0) {
        if (w < 4) load_a<9>(apD0, T, 68, base0, l, Areg);
        else       load_a<8>(apD0, T, 68, base0, l, Areg);
    } else {
        load_a<16>(apD1, T, 128, w * 16, l, Areg);
    }

    // ---- decoder: 64 steps x {L0, L1, fc} phases ----
    for (int t = 0; t < LOUT; t++) {
        if (isL0) {
            f32x16 a0 = {}, a1 = {};
            const unsigned short* B1 = xf[t & 1];
            const unsigned short* B2 = h0f[(t + 1) & 1];
            if (w < 4) compute_ph<9>(B1, 4, B2, base0, Areg, l, a0, a1);
            else       compute_ph<8>(B1, 4, B2, base0, Areg, l, a0, a1);
            reduce_epi(ldsf, a0, a1, w, l, T, biasB + 8192, h0f[t & 1], nullptr, creg);
        }
        gridbar(bar, ep, tid, g);

        if (!isL0) {
            f32x16 a0 = {}, a1 = {};
            const unsigned short* B1 = h0f[t & 1];
            const unsigned short* B2 = h1f[t & 1];
            compute_ph<16>(B1, 64, B2, w * 16, Areg, l, a0, a1);
            reduce_epi(ldsf, a0, a1, w, l, T, biasB + 12288, h1f[(t + 1) & 1], h1km, creg);
        }
        gridbar(bar, ep, tid, g);

        // fc + next-x assembly
        if (g < NENDO) {
            int b_ = tid & 63, kw = tid >> 6;
            float a = 0.0f;
#pragma unroll 8
            for (int i = 0; i < 128; i++) {
                int k = kw * 128 + i;
                a = fmaf(h1km[k * 64 + b_], fcW[g * 1024 + k], a);
            }
            __syncthreads();
            ldsf[kw * 64 + b_] = a;
            __syncthreads();
            if (tid < 64) {
                float s = fcb[g];
#pragma unroll
                for (int j = 0; j < 8; j++) s += ldsf[j * 64 + tid];
                out[tid * (LOUT * NENDO) + t * NENDO + g] = s;
                unsigned short hh = f2bh(s);
                unsigned short hl = f2bh(s - bh2f(hh));
                unsigned short* x2 = xf[(t + 1) & 1];
                x2[frag_off(g, tid, 0)] = hh;
                x2[frag_off(g, tid, 1)] = hl;
            }
        } else if (g == NENDO) {
#pragma unroll
            for (int r = 0; r < 2; r++) {
                int idx = tid + r * 512;
                int e = idx >> 6, b = idx & 63;
                int k = NENDO + e;
                unsigned short* x2 = xf[(t + 1) & 1];
                x2[frag_off(k, b, 0)] = exh[t * 1024 + b * 16 + e];
                x2[frag_off(k, b, 1)] = exl[t * 1024 + b * 16 + e];
            }
        }
        gridbar(bar, ep, tid, g);
    }
}

extern "C" void kernel_launch(void* const* d_in, const int* in_sizes, int n_in,
                              void* d_out, int out_size, void* d_ws, size_t ws_size,
                              hipStream_t stream)
{
    const float* src = (const float*)d_in[0];
    const float* trg = (const float*)d_in[1];
    const float* eWih0 = (const float*)d_in[2];
    const float* eWhh0 = (const float*)d_in[3];
    const float* ebih0 = (const float*)d_in[4];
    const float* ebhh0 = (const float*)d_in[5];
    const float* eWih1 = (const float*)d_in[6];
    const float* eWhh1 = (const float*)d_in[7];
    const float* ebih1 = (const float*)d_in[8];
    const float* ebhh1 = (const float*)d_in[9];
    const float* dWih0 = (const float*)d_in[10];
    const float* dWhh0 = (const float*)d_in[11];
    const float* dbih0 = (const float*)d_in[12];
    const float* dbhh0 = (const float*)d_in[13];
    const float* dWih1 = (const float*)d_in[14];
    const float* dWhh1 = (const float*)d_in[15];
    const float* dbih1 = (const float*)d_in[16];
    const float* dbhh1 = (const float*)d_in[17];
    const float* fcW = (const float*)d_in[18];
    const float* fcb = (const float*)d_in[19];

    char* wsb = (char*)d_ws;
    float* out = (float*)d_out;
    auto U = [&](size_t o) { return (unsigned short*)(wsb + o); };

    pack_a32<<<2048, 256, 0, stream>>>(eWih0, eWhh0, U(O_APE0), 64, 68);
    pack_a32<<<4096, 256, 0, stream>>>(eWih1, eWhh1, U(O_APE1), 1024, 128);
    pack_a32<<<2048, 256, 0, stream>>>(dWih0, dWhh0, U(O_APD0), 64, 68);
    pack_a32<<<4096, 256, 0, stream>>>(dWih1, dWhh1, U(O_APD1), 1024, 128);
    pack_bias_kernel<<<16, 256, 0, stream>>>(ebih0, ebhh0, ebih1, ebhh1,
                                             dbih0, dbhh0, dbih1, dbhh1,
                                             (float*)(wsb + O_BIAS));
    prep_misc<<<1024, 256, 0, stream>>>(src, trg, wsb);

    persist<<<256, 512, 0, stream>>>(wsb, fcW, fcb, out);
}

// Round 5
// 11289.446 us; speedup vs baseline: 1.0592x; 1.0592x over previous
//
#include <hip/hip_runtime.h>
#include <math.h>

#define LIN 256
#define LOUT 64
#define NENDO 48

typedef __attribute__((ext_vector_type(8))) short short8;
typedef __attribute__((ext_vector_type(4))) float f32x4;
typedef __attribute__((ext_vector_type(16))) float f32x16;

// ---------------- ws layout (bytes) ----------------
constexpr size_t O_APE0 = 0;                      // 128 T x 68 c x 2 spl x 512 sh x 2B
constexpr size_t O_APE1 = 17825792;               // 128 x 128 x 2 x 512 x 2
constexpr size_t O_APD0 = 51380224;
constexpr size_t O_APD1 = 69206016;
constexpr size_t O_SRCF = 102760448;              // 256 steps x 16384 B (frag order)
constexpr size_t O_EXH  = 106954752;              // [64t][64b][16e] ushort
constexpr size_t O_EXL  = 107085824;
constexpr size_t O_H0F  = 107216896;              // 2 x 262144 (frag order)
constexpr size_t O_H1F  = 107741184;              // 2 x 262144
constexpr size_t O_XF   = 108265472;              // 2 x 16384
constexpr size_t O_H1KM = 108298240;              // fp32 [1024][64]
constexpr size_t O_BIAS = 108560384;              // 4 x [1024][4] fp32
constexpr size_t O_BAR  = 108625920;              // 2048 ints
// total 108,634,112 B

__device__ __forceinline__ unsigned short f2bh(float x) {
    unsigned int u = __float_as_uint(x);
    unsigned int r = (u + 0x7fffu + ((u >> 16) & 1u)) >> 16;
    return (unsigned short)r;
}
__device__ __forceinline__ float bh2f(unsigned short h) {
    return __uint_as_float(((unsigned int)h) << 16);
}
__device__ __forceinline__ float sigf(float x) { return 1.0f / (1.0f + expf(-x)); }

// frag-order state layout: [ks(16k)][bt(2)][spl(2)][64 lanes][8 e] shorts
// element (k, b): ks=k>>4, lane=(b&31)+32*((k>>3)&1), e=k&7, bt=b>>5
__device__ __forceinline__ size_t frag_off(int k, int b, int spl) {
    return (size_t)(k >> 4) * 2048 + (size_t)(b >> 5) * 1024 + (size_t)spl * 512
         + (size_t)((b & 31) + 32 * ((k >> 3) & 1)) * 8 + (k & 7);
}

// ---------------- A pre-pack: 32-row tiles, 16-k chunks, 32x32x16 A-frag order ----------------
// out[T][c][spl][lane*8+e]: row p = T*32 + (lane&31), k = c*16 + (lane>>5)*8 + e
__global__ void pack_a32(const float* __restrict__ Wx, const float* __restrict__ Wh,
                         unsigned short* __restrict__ out, int KX, int NC)
{
    const int n = 128 * NC * 512;
    for (int j = blockIdx.x * blockDim.x + threadIdx.x; j < n; j += gridDim.x * blockDim.x) {
        int r2 = j & 511;
        int c = (j >> 9) % NC;
        int T = (j >> 9) / NC;
        int l = r2 >> 3, e = r2 & 7;
        int p = T * 32 + (l & 31);
        int hcol = p >> 2, gate = p & 3;
        int k = c * 16 + (l >> 5) * 8 + e;
        float v = (k < KX) ? Wx[(gate * 1024 + hcol) * KX + k]
                           : Wh[(gate * 1024 + hcol) * 1024 + (k - KX)];
        unsigned short h = f2bh(v);
        size_t o = ((size_t)(T * NC + c) * 2) * 512 + r2;
        out[o] = h;
        out[o + 512] = f2bh(v - bh2f(h));
    }
}

__global__ void pack_bias_kernel(const float* a0, const float* b0, const float* a1, const float* b1,
                                 const float* a2, const float* b2, const float* a3, const float* b3,
                                 float* d)
{
    int i = blockIdx.x * blockDim.x + threadIdx.x;
    if (i >= 4096) return;
    int hcol = i >> 2, gate = i & 3, s = (gate << 10) + hcol;
    d[i] = a0[s] + b0[s];
    d[4096 + i] = a1[s] + b1[s];
    d[8192 + i] = a2[s] + b2[s];
    d[12288 + i] = a3[s] + b3[s];
}

// ---------------- misc prep ----------------
__global__ void prep_misc(const float* __restrict__ src, const float* __restrict__ trg,
                          char* __restrict__ wsb)
{
    unsigned short* hz = (unsigned short*)(wsb + O_H0F);   // h0f+h1f contiguous: 524288 shorts
    int* bar = (int*)(wsb + O_BAR);
    unsigned short* srcf = (unsigned short*)(wsb + O_SRCF);
    unsigned short* exh = (unsigned short*)(wsb + O_EXH);
    unsigned short* exl = (unsigned short*)(wsb + O_EXL);
    unsigned short* xf0 = (unsigned short*)(wsb + O_XF);
    const int N0 = 524288, N1 = 2048, N2 = 1048576, N3 = 65536, N4 = 4096;
    const int TOT = N0 + N1 + N2 + N3 + N4;
    for (int i = blockIdx.x * blockDim.x + threadIdx.x; i < TOT; i += gridDim.x * blockDim.x) {
        if (i < N0) {
            hz[i] = 0;
        } else if (i < N0 + N1) {
            bar[i - N0] = 0;
        } else if (i < N0 + N1 + N2) {
            int j = i - (N0 + N1);
            int t = j >> 12, b = (j >> 6) & 63, k = j & 63;
            float v = src[(b * LIN + t) * 64 + k];
            unsigned short h = f2bh(v);
            unsigned short* d = srcf + (size_t)t * 8192;
            d[frag_off(k, b, 0)] = h;
            d[frag_off(k, b, 1)] = f2bh(v - bh2f(h));
        } else if (i < N0 + N1 + N2 + N3) {
            int j = i - (N0 + N1 + N2);
            int t = j >> 10, b = (j >> 4) & 63, e = j & 15;
            float v = trg[(b * LOUT + t) * 64 + NENDO + e];
            unsigned short h = f2bh(v);
            exh[j] = h; exl[j] = f2bh(v - bh2f(h));
        } else {
            int j = i - (N0 + N1 + N2 + N3);
            int b = j >> 6, k = j & 63;
            float v = src[(b * LIN + (LIN - 1)) * 64 + k];
            unsigned short h = f2bh(v);
            xf0[frag_off(k, b, 0)] = h;
            xf0[frag_off(k, b, 1)] = f2bh(v - bh2f(h));
        }
    }
}

// ---------------- persistent kernel helpers ----------------
template <int CNT>
__device__ __forceinline__ void load_a(const unsigned short* __restrict__ ap, int T, int NC,
                                       int base, int l, short8* A)
{
#pragma unroll
    for (int i = 0; i < CNT; i++) {
#pragma unroll
        for (int s = 0; s < 2; s++)
            A[i * 2 + s] = *(const short8*)(ap + (((size_t)T * NC + (base + i)) * 2 + s) * 512 + l * 8);
    }
}

template <int CNT>
__device__ __forceinline__ void compute_ph(const unsigned short* __restrict__ B1, int S,
                                           const unsigned short* __restrict__ B2,
                                           int base, const short8* A, int l,
                                           f32x16& a0, f32x16& a1)
{
#pragma unroll
    for (int i = 0; i < CNT; i++) {
        int ks = base + i;
        const unsigned short* fb = (ks < S) ? (B1 + (size_t)ks * 2048) : (B2 + (size_t)(ks - S) * 2048);
        short8 bh0 = *(const short8*)(fb + l * 8);
        short8 bl0 = *(const short8*)(fb + 512 + l * 8);
        short8 bh1 = *(const short8*)(fb + 1024 + l * 8);
        short8 bl1 = *(const short8*)(fb + 1536 + l * 8);
        short8 ah = A[i * 2], al = A[i * 2 + 1];
        a0 = __builtin_amdgcn_mfma_f32_32x32x16_bf16(ah, bh0, a0, 0, 0, 0);
        a1 = __builtin_amdgcn_mfma_f32_32x32x16_bf16(ah, bh1, a1, 0, 0, 0);
        a0 = __builtin_amdgcn_mfma_f32_32x32x16_bf16(ah, bl0, a0, 0, 0, 0);
        a1 = __builtin_amdgcn_mfma_f32_32x32x16_bf16(ah, bl1, a1, 0, 0, 0);
        a0 = __builtin_amdgcn_mfma_f32_32x32x16_bf16(al, bh0, a0, 0, 0, 0);
        a1 = __builtin_amdgcn_mfma_f32_32x32x16_bf16(al, bh1, a1, 0, 0, 0);
    }
}

// reduce across 8 kt-waves, apply LSTM pointwise, write h frag-order (+ optional k-major f32)
__device__ __forceinline__ void reduce_epi(float* ldsf, f32x16& a0, f32x16& a1,
                                           int w, int l, int T,
                                           const float* __restrict__ biasP,
                                           unsigned short* __restrict__ Hout,
                                           float* __restrict__ km, float* creg)
{
    const int l31 = l & 31, l5 = l >> 5;
    __syncthreads();
#pragma unroll
    for (int j = 0; j < 16; j++) {
        ldsf[((w * 2 + 0) * 16 + j) * 64 + l] = a0[j];
        ldsf[((w * 2 + 1) * 16 + j) * 64 + l] = a1[j];
    }
    __syncthreads();
    if (w < 2) {
#pragma unroll
        for (int q = 0; q < 4; q++) {
            float gv[4];
#pragma unroll
            for (int j = 0; j < 4; j++) {
                float v = 0.0f;
#pragma unroll
                for (int kt = 0; kt < 8; kt++) v += ldsf[((kt * 2 + w) * 16 + (q * 4 + j)) * 64 + l];
                gv[j] = v;
            }
            int hcol = T * 8 + 2 * q + l5;
            int b = w * 32 + l31;
            const f32x4 bv = *(const f32x4*)(biasP + hcol * 4);
            float ig = sigf(gv[0] + bv[0]);
            float fg = sigf(gv[1] + bv[1]);
            float gg = tanhf(gv[2] + bv[2]);
            float og = sigf(gv[3] + bv[3]);
            float cv = fg * creg[q] + ig * gg;
            creg[q] = cv;
            float hv = og * tanhf(cv);
            if (km) km[hcol * 64 + b] = hv;
            unsigned short hh = f2bh(hv);
            unsigned short hl = f2bh(hv - bh2f(hh));
            size_t fo = (size_t)(T >> 1) * 2048 + (size_t)w * 1024
                      + (size_t)(l31 + 32 * (T & 1)) * 8 + (2 * q + l5);
            Hout[fo] = hh;
            Hout[fo + 512] = hl;
        }
    }
}

__device__ __forceinline__ void gridbar(int* bar, int& ep, int tid, int gblk)
{
    __syncthreads();
    ep++;
    if (tid == 0) {
        __threadfence();
        int grp = gblk >> 5;
        int a = atomicAdd(&bar[grp * 32], 1);
        if (a == ep * 32 - 1) atomicAdd(&bar[1024], 1);
        while (__hip_atomic_load(&bar[1024], __ATOMIC_RELAXED, __HIP_MEMORY_SCOPE_AGENT) < ep * 8)
            __builtin_amdgcn_s_sleep(4);
        __threadfence();
    }
    __syncthreads();
}

// ---------------- the persistent kernel ----------------
// __launch_bounds__(512, 2): 2 waves/EU x 4 EU = 8 waves = exactly our 1 block/CU
// -> VGPR cap 256/lane (full file), so Areg[32] (128 VGPR) stays in registers.
// Round-4's missing hint capped VGPR at 128 and spilled all of Areg to scratch
// (811 MB FETCH + 394 MB WRITE per dispatch of pure spill traffic).
__global__ __launch_bounds__(512, 2) void persist(char* __restrict__ wsb,
                                                  const float* __restrict__ fcW,
                                                  const float* __restrict__ fcb,
                                                  float* __restrict__ out)
{
    __shared__ float ldsf[16384];  // 64 KB

    const unsigned short* apE0 = (const unsigned short*)(wsb + O_APE0);
    const unsigned short* apE1 = (const unsigned short*)(wsb + O_APE1);
    const unsigned short* apD0 = (const unsigned short*)(wsb + O_APD0);
    const unsigned short* apD1 = (const unsigned short*)(wsb + O_APD1);
    const unsigned short* srcf = (const unsigned short*)(wsb + O_SRCF);
    const unsigned short* exh = (const unsigned short*)(wsb + O_EXH);
    const unsigned short* exl = (const unsigned short*)(wsb + O_EXL);
    unsigned short* h0f[2] = { (unsigned short*)(wsb + O_H0F), (unsigned short*)(wsb + O_H0F + 262144) };
    unsigned short* h1f[2] = { (unsigned short*)(wsb + O_H1F), (unsigned short*)(wsb + O_H1F + 262144) };
    unsigned short* xf[2] = { (unsigned short*)(wsb + O_XF), (unsigned short*)(wsb + O_XF + 16384) };
    float* h1km = (float*)(wsb + O_H1KM);
    const float* biasB = (const float*)(wsb + O_BIAS);
    int* bar = (int*)(wsb + O_BAR);

    const int tid = threadIdx.x;
    const int l = tid & 63;
    const int w = tid >> 6;            // kt wave id 0..7
    const int g = blockIdx.x;
    const bool isL0 = g < 128;
    const int T = isL0 ? g : g - 128;
    const int base0 = (w < 4) ? w * 9 : 36 + (w - 4) * 8;   // L0-type K split (68 chunks)
    int ep = 0;

    short8 Areg[32];
    float creg[4] = {0.f, 0.f, 0.f, 0.f};

    // ---- load encoder A into registers ----
    if (isL0) {
        if (w < 4) load_a<9>(apE0, T, 68, base0, l, Areg);
        else       load_a<8>(apE0, T, 68, base0, l, Areg);
    } else {
        load_a<16>(apE1, T, 128, w * 16, l, Areg);
    }

    // ---- encoder: 257 slots; slot d runs L0(step d) and L1(step d-1) ----
    for (int d = 0; d <= LIN; d++) {
        if (isL0) {
            if (d < LIN) {
                f32x16 a0 = {}, a1 = {};
                const unsigned short* B1 = srcf + (size_t)d * 8192;
                const unsigned short* B2 = h0f[(d + 1) & 1];
                if (w < 4) compute_ph<9>(B1, 4, B2, base0, Areg, l, a0, a1);
                else       compute_ph<8>(B1, 4, B2, base0, Areg, l, a0, a1);
                reduce_epi(ldsf, a0, a1, w, l, T, biasB, h0f[d & 1], nullptr, creg);
            }
        } else {
            if (d >= 1) {
                f32x16 a0 = {}, a1 = {};
                const unsigned short* B1 = h0f[(d + 1) & 1];
                const unsigned short* B2 = h1f[(d + 1) & 1];
                compute_ph<16>(B1, 64, B2, w * 16, Areg, l, a0, a1);
                reduce_epi(ldsf, a0, a1, w, l, T, biasB + 4096, h1f[d & 1], nullptr, creg);
            }
        }
        gridbar(bar, ep, tid, g);
    }

    // ---- reload A for decoder ----
    if (isL0) {
        if (w < 4) load_a<9>(apD0, T, 68, base0, l, Areg);
        else       load_a<8>(apD0, T, 68, base0, l, Areg);
    } else {
        load_a<16>(apD1, T, 128, w * 16, l, Areg);
    }

    // ---- decoder: 64 steps x {L0, L1, fc} phases ----
    for (int t = 0; t < LOUT; t++) {
        if (isL0) {
            f32x16 a0 = {}, a1 = {};
            const unsigned short* B1 = xf[t & 1];
            const unsigned short* B2 = h0f[(t + 1) & 1];
            if (w < 4) compute_ph<9>(B1, 4, B2, base0, Areg, l, a0, a1);
            else       compute_ph<8>(B1, 4, B2, base0, Areg, l, a0, a1);
            reduce_epi(ldsf, a0, a1, w, l, T, biasB + 8192, h0f[t & 1], nullptr, creg);
        }
        gridbar(bar, ep, tid, g);

        if (!isL0) {
            f32x16 a0 = {}, a1 = {};
            const unsigned short* B1 = h0f[t & 1];
            const unsigned short* B2 = h1f[t & 1];
            compute_ph<16>(B1, 64, B2, w * 16, Areg, l, a0, a1);
            reduce_epi(ldsf, a0, a1, w, l, T, biasB + 12288, h1f[(t + 1) & 1], h1km, creg);
        }
        gridbar(bar, ep, tid, g);

        // fc + next-x assembly
        if (g < NENDO) {
            int b_ = tid & 63, kw = tid >> 6;
            float a = 0.0f;
#pragma unroll 8
            for (int i = 0; i < 128; i++) {
                int k = kw * 128 + i;
                a = fmaf(h1km[k * 64 + b_], fcW[g * 1024 + k], a);
            }
            __syncthreads();
            ldsf[kw * 64 + b_] = a;
            __syncthreads();
            if (tid < 64) {
                float s = fcb[g];
#pragma unroll
                for (int j = 0; j < 8; j++) s += ldsf[j * 64 + tid];
                out[tid * (LOUT * NENDO) + t * NENDO + g] = s;
                unsigned short hh = f2bh(s);
                unsigned short hl = f2bh(s - bh2f(hh));
                unsigned short* x2 = xf[(t + 1) & 1];
                x2[frag_off(g, tid, 0)] = hh;
                x2[frag_off(g, tid, 1)] = hl;
            }
        } else if (g == NENDO) {
#pragma unroll
            for (int r = 0; r < 2; r++) {
                int idx = tid + r * 512;
                int e = idx >> 6, b = idx & 63;
                int k = NENDO + e;
                unsigned short* x2 = xf[(t + 1) & 1];
                x2[frag_off(k, b, 0)] = exh[t * 1024 + b * 16 + e];
                x2[frag_off(k, b, 1)] = exl[t * 1024 + b * 16 + e];
            }
        }
        gridbar(bar, ep, tid, g);
    }
}

extern "C" void kernel_launch(void* const* d_in, const int* in_sizes, int n_in,
                              void* d_out, int out_size, void* d_ws, size_t ws_size,
                              hipStream_t stream)
{
    const float* src = (const float*)d_in[0];
    const float* trg = (const float*)d_in[1];
    const float* eWih0 = (const float*)d_in[2];
    const float* eWhh0 = (const float*)d_in[3];
    const float* ebih0 = (const float*)d_in[4];
    const float* ebhh0 = (const float*)d_in[5];
    const float* eWih1 = (const float*)d_in[6];
    const float* eWhh1 = (const float*)d_in[7];
    const float* ebih1 = (const float*)d_in[8];
    const float* ebhh1 = (const float*)d_in[9];
    const float* dWih0 = (const float*)d_in[10];
    const float* dWhh0 = (const float*)d_in[11];
    const float* dbih0 = (const float*)d_in[12];
    const float* dbhh0 = (const float*)d_in[13];
    const float* dWih1 = (const float*)d_in[14];
    const float* dWhh1 = (const float*)d_in[15];
    const float* dbih1 = (const float*)d_in[16];
    const float* dbhh1 = (const float*)d_in[17];
    const float* fcW = (const float*)d_in[18];
    const float* fcb = (const float*)d_in[19];

    char* wsb = (char*)d_ws;
    float* out = (float*)d_out;
    auto U = [&](size_t o) { return (unsigned short*)(wsb + o); };

    pack_a32<<<2048, 256, 0, stream>>>(eWih0, eWhh0, U(O_APE0), 64, 68);
    pack_a32<<<4096, 256, 0, stream>>>(eWih1, eWhh1, U(O_APE1), 1024, 128);
    pack_a32<<<2048, 256, 0, stream>>>(dWih0, dWhh0, U(O_APD0), 64, 68);
    pack_a32<<<4096, 256, 0, stream>>>(dWih1, dWhh1, U(O_APD1), 1024, 128);
    pack_bias_kernel<<<16, 256, 0, stream>>>(ebih0, ebhh0, ebih1, ebhh1,
                                             dbih0, dbhh0, dbih1, dbhh1,
                                             (float*)(wsb + O_BIAS));
    prep_misc<<<1024, 256, 0, stream>>>(src, trg, wsb);

    persist<<<256, 512, 0, stream>>>(wsb, fcW, fcb, out);
}

// Round 7
// 7360.460 us; speedup vs baseline: 1.6247x; 1.5338x over previous
//
#include <hip/hip_runtime.h>
#include <math.h>

#define LIN 256
#define LOUT 64
#define NENDO 48

typedef __attribute__((ext_vector_type(8))) short short8;
typedef __attribute__((ext_vector_type(4))) float f32x4;
typedef __attribute__((ext_vector_type(16))) float f32x16;

// ---------------- ws layout (bytes) ----------------
constexpr size_t O_APE0 = 0;                      // 128 T x 68 c x 2 spl x 512 sh x 2B
constexpr size_t O_APE1 = 17825792;               // 128 x 128 x 2 x 512 x 2
constexpr size_t O_APD0 = 51380224;
constexpr size_t O_APD1 = 69206016;
constexpr size_t O_SRCF = 102760448;              // 256 steps x 16384 B (frag order)
constexpr size_t O_EXH  = 106954752;              // [64t][64b][16e] ushort
constexpr size_t O_EXL  = 107085824;
constexpr size_t O_H0F  = 107216896;              // 2 x 262144 (frag order)
constexpr size_t O_H1F  = 107741184;              // 2 x 262144
constexpr size_t O_XF   = 108265472;              // 2 x 16384
constexpr size_t O_H1KM = 108298240;              // fp32 [1024][64]
constexpr size_t O_BIAS = 108560384;              // 4 x [1024][4] fp32
constexpr size_t O_BAR  = 108625920;              // 2048 ints
// total 108,634,112 B

__device__ __forceinline__ unsigned short f2bh(float x) {
    unsigned int u = __float_as_uint(x);
    unsigned int r = (u + 0x7fffu + ((u >> 16) & 1u)) >> 16;
    return (unsigned short)r;
}
__device__ __forceinline__ float bh2f(unsigned short h) {
    return __uint_as_float(((unsigned int)h) << 16);
}
__device__ __forceinline__ float sigf(float x) { return 1.0f / (1.0f + expf(-x)); }

// ---- device-coherent (MALL-level) accessors: bypass non-coherent L1/L2 ----
// NOTE: outputs MUST be early-clobber ("=&v"): this is a multi-instruction asm
// block; a plain "=v" output may alias the %4 address pair and the first load
// would clobber the address still read by loads 2-4 (round-6 crash).
__device__ __forceinline__ void load4_cc(const unsigned short* base,
                                         short8& h0, short8& l0, short8& h1, short8& l1)
{
    asm volatile(
        "global_load_dwordx4 %0, %4, off sc0 sc1\n\t"
        "global_load_dwordx4 %1, %4, off offset:1024 sc0 sc1\n\t"
        "global_load_dwordx4 %2, %4, off offset:2048 sc0 sc1\n\t"
        "global_load_dwordx4 %3, %4, off offset:3072 sc0 sc1"
        : "=&v"(h0), "=&v"(l0), "=&v"(h1), "=&v"(l1)
        : "v"(base)
        : "memory");
}
__device__ __forceinline__ void store_us_cc(unsigned short* p, unsigned short v) {
    unsigned int w = v;
    asm volatile("global_store_short %0, %1, off sc0 sc1" :: "v"(p), "v"(w) : "memory");
}
__device__ __forceinline__ void store_f_cc(float* p, float v) {
    asm volatile("global_store_dword %0, %1, off sc0 sc1" :: "v"(p), "v"(v) : "memory");
}
__device__ __forceinline__ void load_f_cc_issue(const float* p, float& dst) {
    asm volatile("global_load_dword %0, %1, off sc0 sc1" : "=v"(dst) : "v"(p) : "memory");
}

// frag-order state layout: [ks(16k)][bt(2)][spl(2)][64 lanes][8 e] shorts
__device__ __forceinline__ size_t frag_off(int k, int b, int spl) {
    return (size_t)(k >> 4) * 2048 + (size_t)(b >> 5) * 1024 + (size_t)spl * 512
         + (size_t)((b & 31) + 32 * ((k >> 3) & 1)) * 8 + (k & 7);
}

// ---------------- A pre-pack: 32-row tiles, 16-k chunks, 32x32x16 A-frag order ----------------
__global__ void pack_a32(const float* __restrict__ Wx, const float* __restrict__ Wh,
                         unsigned short* __restrict__ out, int KX, int NC)
{
    const int n = 128 * NC * 512;
    for (int j = blockIdx.x * blockDim.x + threadIdx.x; j < n; j += gridDim.x * blockDim.x) {
        int r2 = j & 511;
        int c = (j >> 9) % NC;
        int T = (j >> 9) / NC;
        int l = r2 >> 3, e = r2 & 7;
        int p = T * 32 + (l & 31);
        int hcol = p >> 2, gate = p & 3;
        int k = c * 16 + (l >> 5) * 8 + e;
        float v = (k < KX) ? Wx[(gate * 1024 + hcol) * KX + k]
                           : Wh[(gate * 1024 + hcol) * 1024 + (k - KX)];
        unsigned short h = f2bh(v);
        size_t o = ((size_t)(T * NC + c) * 2) * 512 + r2;
        out[o] = h;
        out[o + 512] = f2bh(v - bh2f(h));
    }
}

__global__ void pack_bias_kernel(const float* a0, const float* b0, const float* a1, const float* b1,
                                 const float* a2, const float* b2, const float* a3, const float* b3,
                                 float* d)
{
    int i = blockIdx.x * blockDim.x + threadIdx.x;
    if (i >= 4096) return;
    int hcol = i >> 2, gate = i & 3, s = (gate << 10) + hcol;
    d[i] = a0[s] + b0[s];
    d[4096 + i] = a1[s] + b1[s];
    d[8192 + i] = a2[s] + b2[s];
    d[12288 + i] = a3[s] + b3[s];
}

// ---------------- misc prep ----------------
__global__ void prep_misc(const float* __restrict__ src, const float* __restrict__ trg,
                          char* __restrict__ wsb)
{
    unsigned short* hz = (unsigned short*)(wsb + O_H0F);
    int* bar = (int*)(wsb + O_BAR);
    unsigned short* srcf = (unsigned short*)(wsb + O_SRCF);
    unsigned short* exh = (unsigned short*)(wsb + O_EXH);
    unsigned short* exl = (unsigned short*)(wsb + O_EXL);
    unsigned short* xf0 = (unsigned short*)(wsb + O_XF);
    const int N0 = 524288, N1 = 2048, N2 = 1048576, N3 = 65536, N4 = 4096;
    const int TOT = N0 + N1 + N2 + N3 + N4;
    for (int i = blockIdx.x * blockDim.x + threadIdx.x; i < TOT; i += gridDim.x * blockDim.x) {
        if (i < N0) {
            hz[i] = 0;
        } else if (i < N0 + N1) {
            bar[i - N0] = 0;
        } else if (i < N0 + N1 + N2) {
            int j = i - (N0 + N1);
            int t = j >> 12, b = (j >> 6) & 63, k = j & 63;
            float v = src[(b * LIN + t) * 64 + k];
            unsigned short h = f2bh(v);
            unsigned short* d = srcf + (size_t)t * 8192;
            d[frag_off(k, b, 0)] = h;
            d[frag_off(k, b, 1)] = f2bh(v - bh2f(h));
        } else if (i < N0 + N1 + N2 + N3) {
            int j = i - (N0 + N1 + N2);
            int t = j >> 10, b = (j >> 4) & 63, e = j & 15;
            float v = trg[(b * LOUT + t) * 64 + NENDO + e];
            unsigned short h = f2bh(v);
            exh[j] = h; exl[j] = f2bh(v - bh2f(h));
        } else {
            int j = i - (N0 + N1 + N2 + N3);
            int b = j >> 6, k = j & 63;
            float v = src[(b * LIN + (LIN - 1)) * 64 + k];
            unsigned short h = f2bh(v);
            xf0[frag_off(k, b, 0)] = h;
            xf0[frag_off(k, b, 1)] = f2bh(v - bh2f(h));
        }
    }
}

// ---------------- persistent kernel helpers ----------------
template <int CNT>
__device__ __forceinline__ void load_a(const unsigned short* __restrict__ ap, int T, int NC,
                                       int base, int l, short8* A)
{
#pragma unroll
    for (int i = 0; i < CNT; i++) {
#pragma unroll
        for (int s = 0; s < 2; s++)
            A[i * 2 + s] = *(const short8*)(ap + (((size_t)T * NC + (base + i)) * 2 + s) * 512 + l * 8);
    }
}

// 2-deep pipelined device-coherent B-stream + MFMA
template <int CNT>
__device__ __forceinline__ void compute_ph(const unsigned short* __restrict__ B1, int S,
                                           const unsigned short* __restrict__ B2,
                                           int base, const short8* A, int l,
                                           f32x16& a0, f32x16& a1)
{
    short8 bh0[2], bl0[2], bh1[2], bl1[2];
    auto addr = [&](int i) -> const unsigned short* {
        int ks = base + i;
        const unsigned short* fb = (ks < S) ? (B1 + (size_t)ks * 2048) : (B2 + (size_t)(ks - S) * 2048);
        return fb + l * 8;
    };
    load4_cc(addr(0), bh0[0], bl0[0], bh1[0], bl1[0]);
    __builtin_amdgcn_sched_barrier(0);
#pragma unroll
    for (int i = 0; i < CNT; i++) {
        const int cur = i & 1, nxt = cur ^ 1;
        if (i + 1 < CNT) {
            load4_cc(addr(i + 1), bh0[nxt], bl0[nxt], bh1[nxt], bl1[nxt]);
            __builtin_amdgcn_sched_barrier(0);
            asm volatile("s_waitcnt vmcnt(4)" ::: "memory");
        } else {
            asm volatile("s_waitcnt vmcnt(0)" ::: "memory");
        }
        __builtin_amdgcn_sched_barrier(0);
        short8 ah = A[i * 2], al = A[i * 2 + 1];
        a0 = __builtin_amdgcn_mfma_f32_32x32x16_bf16(ah, bh0[cur], a0, 0, 0, 0);
        a1 = __builtin_amdgcn_mfma_f32_32x32x16_bf16(ah, bh1[cur], a1, 0, 0, 0);
        a0 = __builtin_amdgcn_mfma_f32_32x32x16_bf16(ah, bl0[cur], a0, 0, 0, 0);
        a1 = __builtin_amdgcn_mfma_f32_32x32x16_bf16(ah, bl1[cur], a1, 0, 0, 0);
        a0 = __builtin_amdgcn_mfma_f32_32x32x16_bf16(al, bh0[cur], a0, 0, 0, 0);
        a1 = __builtin_amdgcn_mfma_f32_32x32x16_bf16(al, bh1[cur], a1, 0, 0, 0);
        __builtin_amdgcn_sched_barrier(0);
    }
}

// reduce across 8 kt-waves, apply LSTM pointwise, write h frag-order (+ optional k-major f32)
__device__ __forceinline__ void reduce_epi(float* ldsf, f32x16& a0, f32x16& a1,
                                           int w, int l, int T,
                                           const float* __restrict__ biasP,
                                           unsigned short* __restrict__ Hout,
                                           float* __restrict__ km, float* creg)
{
    const int l31 = l & 31, l5 = l >> 5;
    __syncthreads();
#pragma unroll
    for (int j = 0; j < 16; j++) {
        ldsf[((w * 2 + 0) * 16 + j) * 64 + l] = a0[j];
        ldsf[((w * 2 + 1) * 16 + j) * 64 + l] = a1[j];
    }
    __syncthreads();
    if (w < 2) {
#pragma unroll
        for (int q = 0; q < 4; q++) {
            float gv[4];
#pragma unroll
            for (int j = 0; j < 4; j++) {
                float v = 0.0f;
#pragma unroll
                for (int kt = 0; kt < 8; kt++) v += ldsf[((kt * 2 + w) * 16 + (q * 4 + j)) * 64 + l];
                gv[j] = v;
            }
            int hcol = T * 8 + 2 * q + l5;
            int b = w * 32 + l31;
            const f32x4 bv = *(const f32x4*)(biasP + hcol * 4);
            float ig = sigf(gv[0] + bv[0]);
            float fg = sigf(gv[1] + bv[1]);
            float gg = tanhf(gv[2] + bv[2]);
            float og = sigf(gv[3] + bv[3]);
            float cv = fg * creg[q] + ig * gg;
            creg[q] = cv;
            float hv = og * tanhf(cv);
            if (km) store_f_cc(km + hcol * 64 + b, hv);
            unsigned short hh = f2bh(hv);
            unsigned short hl = f2bh(hv - bh2f(hh));
            size_t fo = (size_t)(T >> 1) * 2048 + (size_t)w * 1024
                      + (size_t)(l31 + 32 * (T & 1)) * 8 + (2 * q + l5);
            store_us_cc(Hout + fo, hh);
            store_us_cc(Hout + fo + 512, hl);
        }
    }
}

// fence-free grid barrier: single RELAXED agent-scope counter + epoch flag.
// All cross-block data moves via sc0sc1 (MALL-coherent); vmcnt(0) guarantees this
// wave's sc1 stores are ack'd at the coherence point before arrival.
__device__ __forceinline__ void gridbar(int* bar, int& ep, int tid)
{
    asm volatile("s_waitcnt vmcnt(0)" ::: "memory");
    __syncthreads();
    ep++;
    if (tid == 0) {
        int a = __hip_atomic_fetch_add(&bar[0], 1, __ATOMIC_RELAXED, __HIP_MEMORY_SCOPE_AGENT);
        if (a == ep * 256 - 1)
            __hip_atomic_store(&bar[256], ep, __ATOMIC_RELAXED, __HIP_MEMORY_SCOPE_AGENT);
        while (__hip_atomic_load(&bar[256], __ATOMIC_RELAXED, __HIP_MEMORY_SCOPE_AGENT) < ep)
            __builtin_amdgcn_s_sleep(2);
    }
    __syncthreads();
}

// ---------------- the persistent kernel ----------------
__global__ __launch_bounds__(512, 2) void persist(char* __restrict__ wsb,
                                                  const float* __restrict__ fcW,
                                                  const float* __restrict__ fcb,
                                                  float* __restrict__ out)
{
    __shared__ float ldsf[16384];  // 64 KB

    const unsigned short* apE0 = (const unsigned short*)(wsb + O_APE0);
    const unsigned short* apE1 = (const unsigned short*)(wsb + O_APE1);
    const unsigned short* apD0 = (const unsigned short*)(wsb + O_APD0);
    const unsigned short* apD1 = (const unsigned short*)(wsb + O_APD1);
    const unsigned short* srcf = (const unsigned short*)(wsb + O_SRCF);
    const unsigned short* exh = (const unsigned short*)(wsb + O_EXH);
    const unsigned short* exl = (const unsigned short*)(wsb + O_EXL);
    unsigned short* h0f[2] = { (unsigned short*)(wsb + O_H0F), (unsigned short*)(wsb + O_H0F + 262144) };
    unsigned short* h1f[2] = { (unsigned short*)(wsb + O_H1F), (unsigned short*)(wsb + O_H1F + 262144) };
    unsigned short* xf[2] = { (unsigned short*)(wsb + O_XF), (unsigned short*)(wsb + O_XF + 16384) };
    float* h1km = (float*)(wsb + O_H1KM);
    const float* biasB = (const float*)(wsb + O_BIAS);
    int* bar = (int*)(wsb + O_BAR);

    const int tid = threadIdx.x;
    const int l = tid & 63;
    const int w = tid >> 6;            // kt wave id 0..7
    const int g = blockIdx.x;
    const bool isL0 = g < 128;
    const int T = isL0 ? g : g - 128;
    const int base0 = (w < 4) ? w * 9 : 36 + (w - 4) * 8;   // L0-type K split (68 chunks)
    int ep = 0;

    short8 Areg[32];
    float creg[4] = {0.f, 0.f, 0.f, 0.f};

    // ---- load encoder A into registers ----
    if (isL0) {
        if (w < 4) load_a<9>(apE0, T, 68, base0, l, Areg);
        else       load_a<8>(apE0, T, 68, base0, l, Areg);
    } else {
        load_a<16>(apE1, T, 128, w * 16, l, Areg);
    }

    // ---- encoder: 257 slots; slot d runs L0(step d) and L1(step d-1) ----
    for (int d = 0; d <= LIN; d++) {
        if (isL0) {
            if (d < LIN) {
                f32x16 a0 = {}, a1 = {};
                const unsigned short* B1 = srcf + (size_t)d * 8192;
                const unsigned short* B2 = h0f[(d + 1) & 1];
                if (w < 4) compute_ph<9>(B1, 4, B2, base0, Areg, l, a0, a1);
                else       compute_ph<8>(B1, 4, B2, base0, Areg, l, a0, a1);
                reduce_epi(ldsf, a0, a1, w, l, T, biasB, h0f[d & 1], nullptr, creg);
            }
        } else {
            if (d >= 1) {
                f32x16 a0 = {}, a1 = {};
                const unsigned short* B1 = h0f[(d + 1) & 1];
                const unsigned short* B2 = h1f[(d + 1) & 1];
                compute_ph<16>(B1, 64, B2, w * 16, Areg, l, a0, a1);
                reduce_epi(ldsf, a0, a1, w, l, T, biasB + 4096, h1f[d & 1], nullptr, creg);
            }
        }
        gridbar(bar, ep, tid);
    }

    // ---- reload A for decoder ----
    if (isL0) {
        if (w < 4) load_a<9>(apD0, T, 68, base0, l, Areg);
        else       load_a<8>(apD0, T, 68, base0, l, Areg);
    } else {
        load_a<16>(apD1, T, 128, w * 16, l, Areg);
    }

    // ---- decoder: 64 steps x {L0, L1, fc} phases ----
    for (int t = 0; t < LOUT; t++) {
        if (isL0) {
            f32x16 a0 = {}, a1 = {};
            const unsigned short* B1 = xf[t & 1];
            const unsigned short* B2 = h0f[(t + 1) & 1];
            if (w < 4) compute_ph<9>(B1, 4, B2, base0, Areg, l, a0, a1);
            else       compute_ph<8>(B1, 4, B2, base0, Areg, l, a0, a1);
            reduce_epi(ldsf, a0, a1, w, l, T, biasB + 8192, h0f[t & 1], nullptr, creg);
        }
        gridbar(bar, ep, tid);

        if (!isL0) {
            f32x16 a0 = {}, a1 = {};
            const unsigned short* B1 = h0f[t & 1];
            const unsigned short* B2 = h1f[t & 1];
            compute_ph<16>(B1, 64, B2, w * 16, Areg, l, a0, a1);
            reduce_epi(ldsf, a0, a1, w, l, T, biasB + 12288, h1f[(t + 1) & 1], h1km, creg);
        }
        gridbar(bar, ep, tid);

        // fc + next-x assembly
        if (g < NENDO) {
            const int b_ = tid & 63, kw = tid >> 6;
            const float* hp = h1km + b_;
            const float* wp = fcW + g * 1024 + kw * 128;
            float vb[2][32];
            float acc = 0.0f;
#pragma unroll
            for (int u = 0; u < 32; u++)
                load_f_cc_issue(hp + (size_t)(kw * 128 + u) * 64, vb[0][u]);
            __builtin_amdgcn_sched_barrier(0);
#pragma unroll
            for (int j = 0; j < 4; j++) {
                if (j + 1 < 4) {
#pragma unroll
                    for (int u = 0; u < 32; u++)
                        load_f_cc_issue(hp + (size_t)(kw * 128 + (j + 1) * 32 + u) * 64, vb[(j + 1) & 1][u]);
                    __builtin_amdgcn_sched_barrier(0);
                    asm volatile("s_waitcnt vmcnt(32)" ::: "memory");
                } else {
                    asm volatile("s_waitcnt vmcnt(0)" ::: "memory");
                }
                __builtin_amdgcn_sched_barrier(0);
#pragma unroll
                for (int u = 0; u < 32; u++)
                    acc = fmaf(vb[j & 1][u], wp[j * 32 + u], acc);
            }
            __syncthreads();
            ldsf[kw * 64 + b_] = acc;
            __syncthreads();
            if (tid < 64) {
                float s = fcb[g];
#pragma unroll
                for (int j = 0; j < 8; j++) s += ldsf[j * 64 + tid];
                out[tid * (LOUT * NENDO) + t * NENDO + g] = s;
                unsigned short hh = f2bh(s);
                unsigned short hl = f2bh(s - bh2f(hh));
                unsigned short* x2 = xf[(t + 1) & 1];
                store_us_cc(x2 + frag_off(g, tid, 0), hh);
                store_us_cc(x2 + frag_off(g, tid, 1), hl);
            }
        } else if (g == NENDO) {
#pragma unroll
            for (int r = 0; r < 2; r++) {
                int idx = tid + r * 512;
                int e = idx >> 6, b = idx & 63;
                int k = NENDO + e;
                unsigned short* x2 = xf[(t + 1) & 1];
                store_us_cc(x2 + frag_off(k, b, 0), exh[t * 1024 + b * 16 + e]);
                store_us_cc(x2 + frag_off(k, b, 1), exl[t * 1024 + b * 16 + e]);
            }
        }
        gridbar(bar, ep, tid);
    }
}

extern "C" void kernel_launch(void* const* d_in, const int* in_sizes, int n_in,
                              void* d_out, int out_size, void* d_ws, size_t ws_size,
                              hipStream_t stream)
{
    const float* src = (const float*)d_in[0];
    const float* trg = (const float*)d_in[1];
    const float* eWih0 = (const float*)d_in[2];
    const float* eWhh0 = (const float*)d_in[3];
    const float* ebih0 = (const float*)d_in[4];
    const float* ebhh0 = (const float*)d_in[5];
    const float* eWih1 = (const float*)d_in[6];
    const float* eWhh1 = (const float*)d_in[7];
    const float* ebih1 = (const float*)d_in[8];
    const float* ebhh1 = (const float*)d_in[9];
    const float* dWih0 = (const float*)d_in[10];
    const float* dWhh0 = (const float*)d_in[11];
    const float* dbih0 = (const float*)d_in[12];
    const float* dbhh0 = (const float*)d_in[13];
    const float* dWih1 = (const float*)d_in[14];
    const float* dWhh1 = (const float*)d_in[15];
    const float* dbih1 = (const float*)d_in[16];
    const float* dbhh1 = (const float*)d_in[17];
    const float* fcW = (const float*)d_in[18];
    const float* fcb = (const float*)d_in[19];

    char* wsb = (char*)d_ws;
    float* out = (float*)d_out;
    auto U = [&](size_t o) { return (unsigned short*)(wsb + o); };

    pack_a32<<<2048, 256, 0, stream>>>(eWih0, eWhh0, U(O_APE0), 64, 68);
    pack_a32<<<4096, 256, 0, stream>>>(eWih1, eWhh1, U(O_APE1), 1024, 128);
    pack_a32<<<2048, 256, 0, stream>>>(dWih0, dWhh0, U(O_APD0), 64, 68);
    pack_a32<<<4096, 256, 0, stream>>>(dWih1, dWhh1, U(O_APD1), 1024, 128);
    pack_bias_kernel<<<16, 256, 0, stream>>>(ebih0, ebhh0, ebih1, ebhh1,
                                             dbih0, dbhh0, dbih1, dbhh1,
                                             (float*)(wsb + O_BIAS));
    prep_misc<<<1024, 256, 0, stream>>>(src, trg, wsb);

    persist<<<256, 512, 0, stream>>>(wsb, fcW, fcb, out);
}